// Round 6
// baseline (2069.526 us; speedup 1.0000x reference)
//
#include <hip/hip_runtime.h>
#include <hip/hip_fp16.h>

#define N_VAR 256
#define M_CON 512
#define BATCH 64
#define SIGMA_C 1e-6f
#define RHO_C 0.1f
#define ALPHA_C 1.6f
#define NITERS 500

// ---------------------------------------------------------------------------
// K1: transpose A [512][256] -> At [256][512] per batch
// ---------------------------------------------------------------------------
__global__ __launch_bounds__(256) void k_transpose(const float* __restrict__ A,
                                                   float* __restrict__ At) {
  __shared__ float tile[32][33];
  int b = blockIdx.z;
  int n0 = blockIdx.x * 32;
  int m0 = blockIdx.y * 32;
  const float* Ab = A + (size_t)b * (M_CON * N_VAR);
  float* Atb = At + (size_t)b * (M_CON * N_VAR);
  int tx = threadIdx.x, ty = threadIdx.y;  // (32, 8)
#pragma unroll
  for (int j = 0; j < 32; j += 8)
    tile[ty + j][tx] = Ab[(size_t)(m0 + ty + j) * N_VAR + n0 + tx];
  __syncthreads();
#pragma unroll
  for (int j = 0; j < 32; j += 8)
    Atb[(size_t)(n0 + ty + j) * M_CON + m0 + tx] = tile[tx][ty + j];
}

// ---------------------------------------------------------------------------
// K2: batched NT GEMM  C[i][j] = alpha * sum_k X[i][k]*Y[j][k]  (+ diag)
// packC=1: write fp16-packed pairs in the ADMM block layout
// Gpk[s][j2][t] with s=gi>>7, j2=(gj&127)>>1, t=((gj>>7)*2+((gi&127)>>6))*64
// + (gi&63). fp32 G never materializes.
// ---------------------------------------------------------------------------
__global__ __launch_bounds__(256) void k_ntgemm(
    const float* __restrict__ X, const float* __restrict__ Y,
    float* __restrict__ C, int I, int J, int K,
    long long bsX, long long bsY, long long bsC, float alpha,
    const float* __restrict__ diagv, int tilesJ, int packC) {
  int b = blockIdx.y;
  int ti = blockIdx.x / tilesJ, tj = blockIdx.x % tilesJ;
  int i0 = ti * 128, j0 = tj * 128;
  const float* Xb = X + (size_t)b * bsX;
  const float* Yb = Y + (size_t)b * bsY;
  float* Cb = C + (size_t)b * bsC;
  __shared__ float Xs[16][128];
  __shared__ float Ys[16][128];
  int tid = threadIdx.x;
  int tx = tid & 15, ty = tid >> 4;
  float acc[8][8];
#pragma unroll
  for (int r = 0; r < 8; ++r)
#pragma unroll
    for (int c = 0; c < 8; ++c) acc[r][c] = 0.0f;

  for (int kk = 0; kk < K; kk += 16) {
#pragma unroll
    for (int v = 0; v < 2; ++v) {
      int idx = v * 256 + tid;
      int row = idx >> 2;
      int k4 = (idx & 3) * 4;
      float4 gx = *(const float4*)(Xb + (size_t)(i0 + row) * K + kk + k4);
      Xs[k4 + 0][row] = gx.x; Xs[k4 + 1][row] = gx.y;
      Xs[k4 + 2][row] = gx.z; Xs[k4 + 3][row] = gx.w;
      float4 gy = *(const float4*)(Yb + (size_t)(j0 + row) * K + kk + k4);
      Ys[k4 + 0][row] = gy.x; Ys[k4 + 1][row] = gy.y;
      Ys[k4 + 2][row] = gy.z; Ys[k4 + 3][row] = gy.w;
    }
    __syncthreads();
#pragma unroll
    for (int k = 0; k < 16; ++k) {
      float xr[8], yr[8];
      *(float4*)&xr[0] = *(float4*)&Xs[k][ty * 8];
      *(float4*)&xr[4] = *(float4*)&Xs[k][ty * 8 + 4];
      *(float4*)&yr[0] = *(float4*)&Ys[k][tx * 8];
      *(float4*)&yr[4] = *(float4*)&Ys[k][tx * 8 + 4];
#pragma unroll
      for (int r = 0; r < 8; ++r)
#pragma unroll
        for (int c = 0; c < 8; ++c) acc[r][c] += xr[r] * yr[c];
    }
    __syncthreads();
  }
  if (packC) {
    unsigned* Cp = (unsigned*)Cb;  // per-batch: 4 slices x 32768 u32
#pragma unroll
    for (int r = 0; r < 8; ++r) {
      int gi = i0 + ty * 8 + r;
      int sl = gi >> 7, rl = gi & 127;
      int rh = rl >> 6, ll = rl & 63;
#pragma unroll
      for (int c = 0; c < 8; c += 2) {
        int gj = j0 + tx * 8 + c;
        int cg = gj >> 7, j2 = (gj & 127) >> 1;
        int t2 = ((((cg << 1) | rh) << 6) | ll);
        __half2 hh = __floats2half2_rn(acc[r][c] * alpha, acc[r][c + 1] * alpha);
        Cp[(size_t)sl * 32768 + j2 * 512 + t2] = *(unsigned*)&hh;
      }
    }
    return;
  }
#pragma unroll
  for (int r = 0; r < 8; ++r) {
    int gi = i0 + ty * 8 + r;
#pragma unroll
    for (int c = 0; c < 8; ++c) {
      int gj = j0 + tx * 8 + c;
      float val = acc[r][c] * alpha;
      if (diagv != nullptr && gi == gj) val += diagv[(size_t)b * N_VAR + gi] + SIGMA_C;
      Cb[(size_t)gi * J + gj] = val;
    }
  }
}

// ---------------------------------------------------------------------------
// K3: BLOCKED Gauss-Jordan inversion, NB=8 (SPD, no pivoting; Schur
// complements of an SPD matrix stay SPD -> stable).
// ---------------------------------------------------------------------------
__global__ __launch_bounds__(512, 2) void k_invert(const float* __restrict__ Mk,
                                                   float* __restrict__ Mi) {
  int b = blockIdx.x;
  const float* src = Mk + (size_t)b * 65536;
  float* dst = Mi + (size_t)b * 65536;
  int t = threadIdx.x;
  int c = t & 255, rh = t >> 8;

  float a[128];
#pragma unroll
  for (int j = 0; j < 128; ++j) a[j] = src[(size_t)(rh * 128 + j) * 256 + c];

  __shared__ float colPan[256][8];     // old pivot-column panel [row][f]
  __shared__ float rowPan[2][8][260];  // raw pivot-row panel [buf][e][c]
  __shared__ float PiSh[64];           // 8x8 pivot-block inverse (flat)
  __shared__ float Rp[8][260];         // scaled pivot-row panel R' [e][c]

  int rh_s = __builtin_amdgcn_readfirstlane(rh);        // wave-uniform
  int cw_s = __builtin_amdgcn_readfirstlane((t >> 6) & 3);  // c-quadrant of wave

  if (rh == 0) {
#pragma unroll
    for (int j = 0; j < 8; ++j) rowPan[0][j][c] = a[j];  // block 0 rows
  }
  __syncthreads();

  for (int s = 0; s < 32; ++s) {
    int kb = s * 8;
    int cur = s & 1, nxt = cur ^ 1;
    int kh = kb >> 7, kj = kb & 127;          // pivot rows: half kh, offset kj
    int khn = (kb + 8) >> 7, kjn = (kb + 8) & 127;
    bool mycol = (c >= kb) && (c < kb + 8);   // per-lane

    // Phase A: threads owning pivot columns dump OLD values (2 waves active)
    if (cw_s == (kb >> 6)) {
      if (mycol) {
        int f = c - kb;
#pragma unroll
        for (int j = 0; j < 128; ++j) colPan[rh * 128 + j][f] = a[j];
      }
    }
    // Phase B (overlapped): wave 0 inverts the 8x8 pivot block via shuffles
    if (t < 64) {
      int e = t >> 3, f = t & 7;
      float p = rowPan[cur][e][kb + f];
#pragma unroll
      for (int k2 = 0; k2 < 8; ++k2) {
        float piv = __shfl(p, k2 * 8 + k2);
        float rv = __shfl(p, k2 * 8 + f);
        float cv = __shfl(p, e * 8 + k2);
        float pivinv = 1.0f / piv;
        float srv = rv * pivinv;
        float gen = p - cv * srv;
        p = gen;
        if (e == k2) p = srv;
        if (f == k2) p = -cv * pivinv;
        if (e == k2 && f == k2) p = pivinv;
      }
      PiSh[t] = p;
    }
    __syncthreads();  // B_mid: colPan + PiSh ready (rowPan[cur] since B_top)

    // Phase C: rp[e] = R'[e][c] in registers; pivot cols carry Pi columns
    float rpan[8];
#pragma unroll
    for (int f2 = 0; f2 < 8; ++f2) rpan[f2] = rowPan[cur][f2][c];
    float rp[8];
#pragma unroll
    for (int e = 0; e < 8; ++e) {
      float4 p0 = *(const float4*)&PiSh[e * 8];      // broadcast
      float4 p1 = *(const float4*)&PiSh[e * 8 + 4];
      rp[e] = p0.x * rpan[0] + p0.y * rpan[1] + p0.z * rpan[2] + p0.w * rpan[3] +
              p1.x * rpan[4] + p1.y * rpan[5] + p1.z * rpan[6] + p1.w * rpan[7];
    }
    if (cw_s == (kb >> 6)) {
      if (mycol) {
        int f = c - kb;
#pragma unroll
        for (int e = 0; e < 8; ++e) rp[e] = PiSh[e * 8 + f];
      }
    }
#pragma unroll
    for (int e = 0; e < 8; ++e) Rp[e][c] = rp[e];  // both rh: same value, benign

    // Phase D: rank-8 update of all 128 owned elements
    bool myhalfk = (rh_s == kh);
    bool stashw = (s != 31) && (rh_s == khn);
#pragma unroll
    for (int j = 0; j < 128; ++j) {
      float4 c0 = *(const float4*)&colPan[rh * 128 + j][0];  // broadcast
      float4 c1 = *(const float4*)&colPan[rh * 128 + j][4];
      float aold = a[j];
      float nv = aold -
                 (c0.x * rp[0] + c0.y * rp[1] + c0.z * rp[2] + c0.w * rp[3] +
                  c1.x * rp[4] + c1.y * rp[5] + c1.z * rp[6] + c1.w * rp[7]);
      if (mycol) nv -= aold;                       // pivot-col correction
      if (myhalfk && j >= kj && j < kj + 8)        // uniform scalar branch
        nv = Rp[j - kj][c];                        // pivot-row override
      a[j] = nv;
      if (stashw && j >= kjn && j < kjn + 8)       // uniform scalar branch
        rowPan[nxt][j - kjn][c] = nv;              // stash next pivot rows
    }
    __syncthreads();  // B_top: stash/colPan/Rp consumption complete
  }

#pragma unroll
  for (int j = 0; j < 128; ++j) dst[(size_t)(rh * 128 + j) * 256 + c] = a[j];
}

// ---------------------------------------------------------------------------
// K4a: h = Minv * q  (column access via symmetry)
// ---------------------------------------------------------------------------
__global__ __launch_bounds__(256) void k_matvec_h(const float* __restrict__ Mi,
                                                  const float* __restrict__ q,
                                                  float* __restrict__ h) {
  int b = blockIdx.x, t = threadIdx.x;
  __shared__ float qs[256];
  qs[t] = q[(size_t)b * 256 + t];
  __syncthreads();
  const float* Mb = Mi + (size_t)b * 65536;
  float acc = 0.0f;
  for (int k = 0; k < 256; ++k) acc += Mb[(size_t)k * 256 + t] * qs[k];
  h[(size_t)b * 256 + t] = acc;
}

// K4b: d = A * h  via At columns
__global__ __launch_bounds__(512) void k_matvec_d(const float* __restrict__ At,
                                                  const float* __restrict__ h,
                                                  float* __restrict__ d) {
  int b = blockIdx.x, t = threadIdx.x;
  __shared__ float hs[256];
  if (t < 256) hs[t] = h[(size_t)b * 256 + t];
  __syncthreads();
  const float* Ab = At + (size_t)b * 131072;
  float acc = 0.0f;
  for (int n = 0; n < 256; ++n) acc += Ab[(size_t)n * 512 + t] * hs[n];
  d[(size_t)b * 512 + t] = acc;
}

// ---------------------------------------------------------------------------
// K6: ADMM loop — round-12: G in LDS as packed fp16, de-risked vs round-11.
// Round-11 died (container, no pytest timing). Two structural risks removed:
//  (1) 136 KB static LDS > the 128 KB proven for plain-HIP static __shared__
//      -> now 120 KB: G planes j2=0..55 in LDS (112 KB), j2=56..63 in 8
//      per-thread VGPRs (every Gpk[j2][t] word is read ONLY by thread t, so
//      LDS is merely an RA-proof private store; 8 regs is far below the RA
//      spill threshold that bit rounds 3-4 at 128).
//  (2) zero-slack residency (1 block/CU x 256 blocks on 256 CUs): at 120 KB
//      LDS the block no longer pins the CU... still 1 block/CU by LDS, but
//      the de-risked size is within the proven envelope.
// Poll: latched + s_sleep(1) backoff (round-1-proven; caps the L3 storm).
// Everything else (packed-G producer, tag/parity exchange, 1 barrier/iter,
// update math) identical to round-11 = protocol of rounds 0-4.
// ---------------------------------------------------------------------------
__global__ __launch_bounds__(512) void k_admm4(
    const unsigned* __restrict__ Gpk_g, const float* __restrict__ dvec,
    const float* __restrict__ lv, const float* __restrict__ uv,
    unsigned long long* __restrict__ wtag, float* __restrict__ Sbuf) {
  int g = blockIdx.x;
  int b = (g & 7) + 8 * ((g >> 3) & 7);
  int s = g >> 6;
  int t = threadIdx.x;
  int l = t & 63, wv = t >> 6;
  int rh = wv & 1, cg = wv >> 1;
  int c0 = cg * 128;
  int row_local = rh * 64 + l;

  __shared__ unsigned Gpk[56][512];                 // 112 KB packed fp16 G
  __shared__ __align__(16) float wbufp[8][128];     // wave-private w windows
  __shared__ float part[2][4][128];                 // parity-buffered partials

  // Stage this thread's G column (words consumed only by this thread).
  const unsigned* gsrc = Gpk_g + (size_t)(b * 4 + s) * 32768;
#pragma unroll
  for (int j2 = 0; j2 < 56; ++j2) Gpk[j2][t] = gsrc[j2 * 512 + t];
  unsigned gq[8];
#pragma unroll
  for (int j2 = 0; j2 < 8; ++j2) gq[j2] = gsrc[(56 + j2) * 512 + t];
#pragma unroll
  for (int j2 = 0; j2 < 8; ++j2) asm volatile("" : "+v"(gq[j2]));

  float zreg = 0.0f, yreg = 0.0f, Sreg = 0.0f;
  float lreg = 0.0f, ureg = 0.0f, dreg = 0.0f;
  if (t < 128) {
    lreg = lv[(size_t)b * 512 + s * 128 + t];
    ureg = uv[(size_t)b * 512 + s * 128 + t];
    dreg = dvec[(size_t)b * 512 + s * 128 + t];
  }
  wbufp[wv][l] = 0.0f;        // w_0 = 0
  wbufp[wv][64 + l] = 0.0f;

  unsigned long long* wt0 = wtag + (size_t)b * 512;
  unsigned long long* wt1 = wtag + 32768 + (size_t)b * 512;
  const float* wrow = wbufp[wv];

  for (int it = 0; it < NITERS; ++it) {
    if (it > 0) {
      // latched poll: 2 words/lane cover this wave's 128-col window
      unsigned long long* wp = (it & 1) ? wt1 : wt0;
      unsigned want = (unsigned)it;
      unsigned long long v0 = __hip_atomic_load(&wp[c0 + l], __ATOMIC_RELAXED,
                                                __HIP_MEMORY_SCOPE_AGENT);
      unsigned long long v1 = __hip_atomic_load(&wp[c0 + 64 + l], __ATOMIC_RELAXED,
                                                __HIP_MEMORY_SCOPE_AGENT);
      bool g0 = ((unsigned)(v0 >> 32) == want);
      bool g1 = ((unsigned)(v1 >> 32) == want);
      while (!__all(g0 && g1)) {
        __builtin_amdgcn_s_sleep(1);
        if (!g0) {
          unsigned long long x = __hip_atomic_load(
              &wp[c0 + l], __ATOMIC_RELAXED, __HIP_MEMORY_SCOPE_AGENT);
          if ((unsigned)(x >> 32) == want) { v0 = x; g0 = true; }
        }
        if (!g1) {
          unsigned long long x = __hip_atomic_load(
              &wp[c0 + 64 + l], __ATOMIC_RELAXED, __HIP_MEMORY_SCOPE_AGENT);
          if ((unsigned)(x >> 32) == want) { v1 = x; g1 = true; }
        }
      }
      wbufp[wv][l] = __uint_as_float((unsigned)(v0 & 0xffffffffu));
      wbufp[wv][64 + l] = __uint_as_float((unsigned)(v1 & 0xffffffffu));
      // same-wave ds_write -> ds_read: in-order, compiler inserts lgkmcnt
    }

    float acc = 0.0f;
#pragma unroll
    for (int j2 = 0; j2 < 56; j2 += 2) {
      float4 wq = *(const float4*)&wrow[j2 * 2];    // broadcast (uniform addr)
      unsigned ga = Gpk[j2][t];
      unsigned gb = Gpk[j2 + 1][t];
      float2 fa = __half22float2(*(__half2*)&ga);
      float2 fb = __half22float2(*(__half2*)&gb);
      acc += fa.x * wq.x + fa.y * wq.y + fb.x * wq.z + fb.y * wq.w;
    }
#pragma unroll
    for (int j2 = 56; j2 < 64; j2 += 2) {
      float4 wq = *(const float4*)&wrow[j2 * 2];
      float2 fa = __half22float2(*(__half2*)&gq[j2 - 56]);
      float2 fb = __half22float2(*(__half2*)&gq[j2 - 55]);
      acc += fa.x * wq.x + fa.y * wq.y + fb.x * wq.z + fb.y * wq.w;
    }
    int pp = it & 1;
    part[pp][cg][row_local] = acc;
    __syncthreads();  // the ONLY barrier: partials of iter `it` visible

    if (t < 128) {
      float w_old = RHO_C * zreg - yreg;
      Sreg = w_old - 0.6f * Sreg;
      float p = part[pp][0][t] + part[pp][1][t] + part[pp][2][t] +
                part[pp][3][t];
      float zt = p - dreg;
      float zh = ALPHA_C * zt + (1.0f - ALPHA_C) * zreg;
      float zc = zh + yreg * (1.0f / RHO_C);
      zc = fminf(fmaxf(zc, lreg), ureg);
      yreg += RHO_C * (zh - zc);
      zreg = zc;
      if (it < NITERS - 1) {
        float wn = RHO_C * zreg - yreg;
        unsigned long long pk =
            ((unsigned long long)(unsigned)(it + 1) << 32) |
            (unsigned long long)__float_as_uint(wn);
        unsigned long long* wp = ((it + 1) & 1) ? wt1 : wt0;
        __hip_atomic_store(&wp[s * 128 + t], pk, __ATOMIC_RELAXED,
                           __HIP_MEMORY_SCOPE_AGENT);
      }
    }
  }

  if (t < 128) Sbuf[(size_t)b * 512 + s * 128 + t] = Sreg;
}

// ---------------------------------------------------------------------------
// K7: epilogue  x = Minv * (alpha * A^T S - q)
// ---------------------------------------------------------------------------
__global__ __launch_bounds__(256) void k_final(
    const float* __restrict__ A, const float* __restrict__ q,
    const float* __restrict__ Mi, const float* __restrict__ Sbuf,
    float* __restrict__ xout) {
  int b = blockIdx.x, t = threadIdx.x;
  __shared__ float Ssh[512];
  __shared__ float uu[256];
  for (int i = t; i < 512; i += 256) Ssh[i] = Sbuf[(size_t)b * 512 + i];
  __syncthreads();
  const float* Ab = A + (size_t)b * 131072;
  float acc = 0.0f;
  for (int m = 0; m < 512; ++m) acc += Ab[(size_t)m * 256 + t] * Ssh[m];
  uu[t] = ALPHA_C * acc - q[(size_t)b * 256 + t];
  __syncthreads();
  const float* Mb = Mi + (size_t)b * 65536;
  float x = 0.0f;
  for (int kk = 0; kk < 256; ++kk) x += Mb[(size_t)kk * 256 + t] * uu[kk];
  xout[(size_t)b * 256 + t] = x;
}

// ---------------------------------------------------------------------------
extern "C" void kernel_launch(void* const* d_in, const int* in_sizes, int n_in,
                              void* d_out, int out_size, void* d_ws, size_t ws_size,
                              hipStream_t stream) {
  (void)in_sizes; (void)n_in; (void)out_size; (void)ws_size;
  const float* P = (const float*)d_in[0];
  const float* q = (const float*)d_in[1];
  const float* Av = (const float*)d_in[2];
  const float* lv = (const float*)d_in[3];
  const float* uv = (const float*)d_in[4];
  float* xout = (float*)d_out;

  float* ws = (float*)d_ws;
  float* At = ws;                       // 64*256*512; dies after k_matvec_d
  float* F  = ws;                       // alias of At; dies after ntgemm G
  float* Mi = ws + 8388608;             // 64*256*256
  float* Mk = ws + 12582912;            // dies after k_invert
  float* Gp = ws + 12582912;            // packed fp16 G: 64*131072 u32 = 32MB
  float* hv = ws + 29360128;            // 64*256
  float* dv = ws + 29376512;            // 64*512
  float* Sbuf = ws + 29409280;          // 64*512
  unsigned long long* wtag = (unsigned long long*)ws;  // overlays dead At/F
                                        // (F-GEMM rewrites the region each
                                        //  launch -> stale tags scrubbed)

  k_transpose<<<dim3(8, 16, 64), dim3(32, 8), 0, stream>>>(Av, At);
  k_ntgemm<<<dim3(4, 64), 256, 0, stream>>>(At, At, Mk, 256, 256, 512,
                                            131072LL, 131072LL, 65536LL,
                                            RHO_C, P, 2, 0);
  k_invert<<<64, 512, 0, stream>>>(Mk, Mi);
  k_matvec_h<<<64, 256, 0, stream>>>(Mi, q, hv);
  k_matvec_d<<<64, 512, 0, stream>>>(At, hv, dv);
  k_ntgemm<<<dim3(8, 64), 256, 0, stream>>>(Av, Mi, F, 512, 256, 256,
                                            131072LL, 65536LL, 131072LL,
                                            1.0f, nullptr, 2, 0);
  // G-GEMM writes packed fp16 directly (bsC in u32 units: 4*32768 per batch)
  k_ntgemm<<<dim3(16, 64), 256, 0, stream>>>(F, Av, Gp, 512, 512, 256,
                                             131072LL, 131072LL, 131072LL,
                                             1.0f, nullptr, 4, 1);
  k_admm4<<<256, 512, 0, stream>>>((const unsigned*)Gp, dv, lv, uv, wtag, Sbuf);
  k_final<<<64, 256, 0, stream>>>(Av, q, Mi, Sbuf, xout);
}

// Round 7
// 1541.417 us; speedup vs baseline: 1.3426x; 1.3426x over previous
//
#include <hip/hip_runtime.h>
#include <hip/hip_fp16.h>

#define N_VAR 256
#define M_CON 512
#define BATCH 64
#define SIGMA_C 1e-6f
#define RHO_C 0.1f
#define ALPHA_C 1.6f
#define NITERS 500

// ---------------------------------------------------------------------------
// K1: transpose A [512][256] -> At [256][512] per batch
// ---------------------------------------------------------------------------
__global__ __launch_bounds__(256) void k_transpose(const float* __restrict__ A,
                                                   float* __restrict__ At) {
  __shared__ float tile[32][33];
  int b = blockIdx.z;
  int n0 = blockIdx.x * 32;
  int m0 = blockIdx.y * 32;
  const float* Ab = A + (size_t)b * (M_CON * N_VAR);
  float* Atb = At + (size_t)b * (M_CON * N_VAR);
  int tx = threadIdx.x, ty = threadIdx.y;  // (32, 8)
#pragma unroll
  for (int j = 0; j < 32; j += 8)
    tile[ty + j][tx] = Ab[(size_t)(m0 + ty + j) * N_VAR + n0 + tx];
  __syncthreads();
#pragma unroll
  for (int j = 0; j < 32; j += 8)
    Atb[(size_t)(n0 + ty + j) * M_CON + m0 + tx] = tile[tx][ty + j];
}

// ---------------------------------------------------------------------------
// K2: batched NT GEMM  C[i][j] = alpha * sum_k X[i][k]*Y[j][k]  (+ diag)
// packC=1: write fp16-packed pairs in the ADMM block layout
// Gpk[s][j2][t2] with s=gi>>7, j2=(gj&127)>>1,
// t2=((gj>>7)*2+((gi&127)>>6))*64 + (gi&63). fp32 G never materializes.
// (Layout proven correct in round 6.)
// ---------------------------------------------------------------------------
__global__ __launch_bounds__(256) void k_ntgemm(
    const float* __restrict__ X, const float* __restrict__ Y,
    float* __restrict__ C, int I, int J, int K,
    long long bsX, long long bsY, long long bsC, float alpha,
    const float* __restrict__ diagv, int tilesJ, int packC) {
  int b = blockIdx.y;
  int ti = blockIdx.x / tilesJ, tj = blockIdx.x % tilesJ;
  int i0 = ti * 128, j0 = tj * 128;
  const float* Xb = X + (size_t)b * bsX;
  const float* Yb = Y + (size_t)b * bsY;
  float* Cb = C + (size_t)b * bsC;
  __shared__ float Xs[16][128];
  __shared__ float Ys[16][128];
  int tid = threadIdx.x;
  int tx = tid & 15, ty = tid >> 4;
  float acc[8][8];
#pragma unroll
  for (int r = 0; r < 8; ++r)
#pragma unroll
    for (int c = 0; c < 8; ++c) acc[r][c] = 0.0f;

  for (int kk = 0; kk < K; kk += 16) {
#pragma unroll
    for (int v = 0; v < 2; ++v) {
      int idx = v * 256 + tid;
      int row = idx >> 2;
      int k4 = (idx & 3) * 4;
      float4 gx = *(const float4*)(Xb + (size_t)(i0 + row) * K + kk + k4);
      Xs[k4 + 0][row] = gx.x; Xs[k4 + 1][row] = gx.y;
      Xs[k4 + 2][row] = gx.z; Xs[k4 + 3][row] = gx.w;
      float4 gy = *(const float4*)(Yb + (size_t)(j0 + row) * K + kk + k4);
      Ys[k4 + 0][row] = gy.x; Ys[k4 + 1][row] = gy.y;
      Ys[k4 + 2][row] = gy.z; Ys[k4 + 3][row] = gy.w;
    }
    __syncthreads();
#pragma unroll
    for (int k = 0; k < 16; ++k) {
      float xr[8], yr[8];
      *(float4*)&xr[0] = *(float4*)&Xs[k][ty * 8];
      *(float4*)&xr[4] = *(float4*)&Xs[k][ty * 8 + 4];
      *(float4*)&yr[0] = *(float4*)&Ys[k][tx * 8];
      *(float4*)&yr[4] = *(float4*)&Ys[k][tx * 8 + 4];
#pragma unroll
      for (int r = 0; r < 8; ++r)
#pragma unroll
        for (int c = 0; c < 8; ++c) acc[r][c] += xr[r] * yr[c];
    }
    __syncthreads();
  }
  if (packC) {
    unsigned* Cp = (unsigned*)Cb;  // per-batch: 4 slices x 32768 u32
#pragma unroll
    for (int r = 0; r < 8; ++r) {
      int gi = i0 + ty * 8 + r;
      int sl = gi >> 7, rl = gi & 127;
      int rh = rl >> 6, ll = rl & 63;
#pragma unroll
      for (int c = 0; c < 8; c += 2) {
        int gj = j0 + tx * 8 + c;
        int cg = gj >> 7, j2 = (gj & 127) >> 1;
        int t2 = ((((cg << 1) | rh) << 6) | ll);
        __half2 hh = __floats2half2_rn(acc[r][c] * alpha, acc[r][c + 1] * alpha);
        Cp[(size_t)sl * 32768 + j2 * 512 + t2] = *(unsigned*)&hh;
      }
    }
    return;
  }
#pragma unroll
  for (int r = 0; r < 8; ++r) {
    int gi = i0 + ty * 8 + r;
#pragma unroll
    for (int c = 0; c < 8; ++c) {
      int gj = j0 + tx * 8 + c;
      float val = acc[r][c] * alpha;
      if (diagv != nullptr && gi == gj) val += diagv[(size_t)b * N_VAR + gi] + SIGMA_C;
      Cb[(size_t)gi * J + gj] = val;
    }
  }
}

// ---------------------------------------------------------------------------
// K3: BLOCKED Gauss-Jordan inversion, NB=8 (SPD, no pivoting; Schur
// complements of an SPD matrix stay SPD -> stable).
// ---------------------------------------------------------------------------
__global__ __launch_bounds__(512, 2) void k_invert(const float* __restrict__ Mk,
                                                   float* __restrict__ Mi) {
  int b = blockIdx.x;
  const float* src = Mk + (size_t)b * 65536;
  float* dst = Mi + (size_t)b * 65536;
  int t = threadIdx.x;
  int c = t & 255, rh = t >> 8;

  float a[128];
#pragma unroll
  for (int j = 0; j < 128; ++j) a[j] = src[(size_t)(rh * 128 + j) * 256 + c];

  __shared__ float colPan[256][8];     // old pivot-column panel [row][f]
  __shared__ float rowPan[2][8][260];  // raw pivot-row panel [buf][e][c]
  __shared__ float PiSh[64];           // 8x8 pivot-block inverse (flat)
  __shared__ float Rp[8][260];         // scaled pivot-row panel R' [e][c]

  int rh_s = __builtin_amdgcn_readfirstlane(rh);        // wave-uniform
  int cw_s = __builtin_amdgcn_readfirstlane((t >> 6) & 3);  // c-quadrant of wave

  if (rh == 0) {
#pragma unroll
    for (int j = 0; j < 8; ++j) rowPan[0][j][c] = a[j];  // block 0 rows
  }
  __syncthreads();

  for (int s = 0; s < 32; ++s) {
    int kb = s * 8;
    int cur = s & 1, nxt = cur ^ 1;
    int kh = kb >> 7, kj = kb & 127;          // pivot rows: half kh, offset kj
    int khn = (kb + 8) >> 7, kjn = (kb + 8) & 127;
    bool mycol = (c >= kb) && (c < kb + 8);   // per-lane

    // Phase A: threads owning pivot columns dump OLD values (2 waves active)
    if (cw_s == (kb >> 6)) {
      if (mycol) {
        int f = c - kb;
#pragma unroll
        for (int j = 0; j < 128; ++j) colPan[rh * 128 + j][f] = a[j];
      }
    }
    // Phase B (overlapped): wave 0 inverts the 8x8 pivot block via shuffles
    if (t < 64) {
      int e = t >> 3, f = t & 7;
      float p = rowPan[cur][e][kb + f];
#pragma unroll
      for (int k2 = 0; k2 < 8; ++k2) {
        float piv = __shfl(p, k2 * 8 + k2);
        float rv = __shfl(p, k2 * 8 + f);
        float cv = __shfl(p, e * 8 + k2);
        float pivinv = 1.0f / piv;
        float srv = rv * pivinv;
        float gen = p - cv * srv;
        p = gen;
        if (e == k2) p = srv;
        if (f == k2) p = -cv * pivinv;
        if (e == k2 && f == k2) p = pivinv;
      }
      PiSh[t] = p;
    }
    __syncthreads();  // B_mid: colPan + PiSh ready (rowPan[cur] since B_top)

    // Phase C: rp[e] = R'[e][c] in registers; pivot cols carry Pi columns
    float rpan[8];
#pragma unroll
    for (int f2 = 0; f2 < 8; ++f2) rpan[f2] = rowPan[cur][f2][c];
    float rp[8];
#pragma unroll
    for (int e = 0; e < 8; ++e) {
      float4 p0 = *(const float4*)&PiSh[e * 8];      // broadcast
      float4 p1 = *(const float4*)&PiSh[e * 8 + 4];
      rp[e] = p0.x * rpan[0] + p0.y * rpan[1] + p0.z * rpan[2] + p0.w * rpan[3] +
              p1.x * rpan[4] + p1.y * rpan[5] + p1.z * rpan[6] + p1.w * rpan[7];
    }
    if (cw_s == (kb >> 6)) {
      if (mycol) {
        int f = c - kb;
#pragma unroll
        for (int e = 0; e < 8; ++e) rp[e] = PiSh[e * 8 + f];
      }
    }
#pragma unroll
    for (int e = 0; e < 8; ++e) Rp[e][c] = rp[e];  // both rh: same value, benign

    // Phase D: rank-8 update of all 128 owned elements
    bool myhalfk = (rh_s == kh);
    bool stashw = (s != 31) && (rh_s == khn);
#pragma unroll
    for (int j = 0; j < 128; ++j) {
      float4 c0 = *(const float4*)&colPan[rh * 128 + j][0];  // broadcast
      float4 c1 = *(const float4*)&colPan[rh * 128 + j][4];
      float aold = a[j];
      float nv = aold -
                 (c0.x * rp[0] + c0.y * rp[1] + c0.z * rp[2] + c0.w * rp[3] +
                  c1.x * rp[4] + c1.y * rp[5] + c1.z * rp[6] + c1.w * rp[7]);
      if (mycol) nv -= aold;                       // pivot-col correction
      if (myhalfk && j >= kj && j < kj + 8)        // uniform scalar branch
        nv = Rp[j - kj][c];                        // pivot-row override
      a[j] = nv;
      if (stashw && j >= kjn && j < kjn + 8)       // uniform scalar branch
        rowPan[nxt][j - kjn][c] = nv;              // stash next pivot rows
    }
    __syncthreads();  // B_top: stash/colPan/Rp consumption complete
  }

#pragma unroll
  for (int j = 0; j < 128; ++j) dst[(size_t)(rh * 128 + j) * 256 + c] = a[j];
}

// ---------------------------------------------------------------------------
// K4a: h = Minv * q  (column access via symmetry)
// ---------------------------------------------------------------------------
__global__ __launch_bounds__(256) void k_matvec_h(const float* __restrict__ Mi,
                                                  const float* __restrict__ q,
                                                  float* __restrict__ h) {
  int b = blockIdx.x, t = threadIdx.x;
  __shared__ float qs[256];
  qs[t] = q[(size_t)b * 256 + t];
  __syncthreads();
  const float* Mb = Mi + (size_t)b * 65536;
  float acc = 0.0f;
  for (int k = 0; k < 256; ++k) acc += Mb[(size_t)k * 256 + t] * qs[k];
  h[(size_t)b * 256 + t] = acc;
}

// K4b: d = A * h  via At columns
__global__ __launch_bounds__(512) void k_matvec_d(const float* __restrict__ At,
                                                  const float* __restrict__ h,
                                                  float* __restrict__ d) {
  int b = blockIdx.x, t = threadIdx.x;
  __shared__ float hs[256];
  if (t < 256) hs[t] = h[(size_t)b * 256 + t];
  __syncthreads();
  const float* Ab = At + (size_t)b * 131072;
  float acc = 0.0f;
  for (int n = 0; n < 256; ++n) acc += Ab[(size_t)n * 512 + t] * hs[n];
  d[(size_t)b * 512 + t] = acc;
}

// ---------------------------------------------------------------------------
// K6: ADMM loop — round-13: round-1/4 skeleton (fastest measured, 713-749)
// with G streamed from GLOBAL as packed fp16 (round-6-proven layout).
// Round-6 post-mortem: G-in-LDS was SLOWER (1250 us) — ds_read issue cost
// (~5.8 cy/b32) + LDS latency with only 2 waves/SIMD serialized the loop;
// the global/scratch path pipelines deeply via vmcnt. But rounds 0-4 were
// L2-BW-bound on fp32 G (67 MB/iter ~ 44 TB/s aggregate). So: keep the
// global-stream pipe, HALVE the bytes. fp16 G = 33.5 MB/iter, fits entirely
// in the 32 MB aggregate L2 (2 MB G per XCD's 4 MB slice); 64 dword loads
// + 128 cvt + 128 FMA per thread per iter. w stays fp32 (accuracy: only G
// is quantized, absmax 0.043 proven in round 6).
// Exchange protocol/barrier/update byte-identical to rounds 1-4.
// Col map check: load (hc*32+4j+m)*512 + cg*128 + l (+64 for row1) ->
// global col = wv*64 + 8j + 2m{,+1}, rows s*128+l / s*128+64+l.
// ---------------------------------------------------------------------------
__global__ __launch_bounds__(512) void k_admm4(
    const unsigned* __restrict__ Gpk_g, const float* __restrict__ dvec,
    const float* __restrict__ lv, const float* __restrict__ uv,
    unsigned long long* __restrict__ wtag, float* __restrict__ Sbuf) {
  int g = blockIdx.x;
  int b = (g & 7) + 8 * ((g >> 3) & 7);
  int s = g >> 6;
  int t = threadIdx.x;
  int l = t & 63, wv = t >> 6;
  int c0 = wv * 64;
  int cg = wv >> 1, hc = wv & 1;

  __shared__ __align__(16) float wbuf[8][64];  // wave-private w windows
  __shared__ float part[2][8][128];            // parity double-buffered partials

  // Packed-G base for this thread: row0 at +0, row1 at +64 (t2 layout);
  // column pair jj at offset jj*512.
  const unsigned* gsrc =
      Gpk_g + (size_t)(b * 4 + s) * 32768 + (size_t)(hc * 32) * 512 + cg * 128 + l;

  float zreg = 0.0f, yreg = 0.0f, Sreg = 0.0f;
  float lreg = 0.0f, ureg = 0.0f, dreg = 0.0f;
  if (t < 128) {
    lreg = lv[(size_t)b * 512 + s * 128 + t];
    ureg = uv[(size_t)b * 512 + s * 128 + t];
    dreg = dvec[(size_t)b * 512 + s * 128 + t];
  }
  wbuf[wv][l] = 0.0f;  // w_0 = 0

  unsigned long long* wt0 = wtag + (size_t)b * 512;
  unsigned long long* wt1 = wtag + 32768 + (size_t)b * 512;
  const float4* wq4 = (const float4*)(wbuf[wv]);

  for (int it = 0; it < NITERS; ++it) {
    if (it > 0) {
      // latched poll of my wave's 64-element window: tag == it, buffer (it&1)
      unsigned long long* wp = (it & 1) ? wt1 : wt0;
      unsigned want = (unsigned)it;
      unsigned long long v = __hip_atomic_load(&wp[c0 + l], __ATOMIC_RELAXED,
                                               __HIP_MEMORY_SCOPE_AGENT);
      bool got = ((unsigned)(v >> 32) == want);
      while (!__all(got)) {
        if (!got) {
          unsigned long long v2 = __hip_atomic_load(
              &wp[c0 + l], __ATOMIC_RELAXED, __HIP_MEMORY_SCOPE_AGENT);
          if ((unsigned)(v2 >> 32) == want) { v = v2; got = true; }
        }
      }
      wbuf[wv][l] = __uint_as_float((unsigned)(v & 0xffffffffu));
      // same-wave ds_write -> ds_read: in-order, compiler inserts lgkmcnt
    }

    float r0a = 0.f, r0b = 0.f, r1a = 0.f, r1b = 0.f;
#pragma unroll
    for (int j = 0; j < 8; ++j) {
      float4 wa = wq4[2 * j];
      float4 wc = wq4[2 * j + 1];
      unsigned a0 = gsrc[(4 * j + 0) * 512];
      unsigned a1 = gsrc[(4 * j + 1) * 512];
      unsigned a2 = gsrc[(4 * j + 2) * 512];
      unsigned a3 = gsrc[(4 * j + 3) * 512];
      unsigned b0 = gsrc[(4 * j + 0) * 512 + 64];
      unsigned b1 = gsrc[(4 * j + 1) * 512 + 64];
      unsigned b2 = gsrc[(4 * j + 2) * 512 + 64];
      unsigned b3 = gsrc[(4 * j + 3) * 512 + 64];
      float2 fa0 = __half22float2(*(__half2*)&a0);
      float2 fa1 = __half22float2(*(__half2*)&a1);
      float2 fa2 = __half22float2(*(__half2*)&a2);
      float2 fa3 = __half22float2(*(__half2*)&a3);
      float2 fb0 = __half22float2(*(__half2*)&b0);
      float2 fb1 = __half22float2(*(__half2*)&b1);
      float2 fb2 = __half22float2(*(__half2*)&b2);
      float2 fb3 = __half22float2(*(__half2*)&b3);
      r0a += fa0.x * wa.x + fa0.y * wa.y + fa1.x * wa.z + fa1.y * wa.w;
      r0b += fa2.x * wc.x + fa2.y * wc.y + fa3.x * wc.z + fa3.y * wc.w;
      r1a += fb0.x * wa.x + fb0.y * wa.y + fb1.x * wa.z + fb1.y * wa.w;
      r1b += fb2.x * wc.x + fb2.y * wc.y + fb3.x * wc.z + fb3.y * wc.w;
    }
    int pp = it & 1;
    part[pp][wv][l] = r0a + r0b;
    part[pp][wv][64 + l] = r1a + r1b;
    __syncthreads();  // the ONLY barrier: partials of iter `it` visible

    if (t < 128) {
      float w_old = RHO_C * zreg - yreg;
      Sreg = w_old - 0.6f * Sreg;
      float p = part[pp][0][t] + part[pp][1][t] + part[pp][2][t] +
                part[pp][3][t] + part[pp][4][t] + part[pp][5][t] +
                part[pp][6][t] + part[pp][7][t];
      float zt = p - dreg;
      float zh = ALPHA_C * zt + (1.0f - ALPHA_C) * zreg;
      float zc = zh + yreg * (1.0f / RHO_C);
      zc = fminf(fmaxf(zc, lreg), ureg);
      yreg += RHO_C * (zh - zc);
      zreg = zc;
      if (it < NITERS - 1) {
        float wn = RHO_C * zreg - yreg;
        unsigned long long pk =
            ((unsigned long long)(unsigned)(it + 1) << 32) |
            (unsigned long long)__float_as_uint(wn);
        unsigned long long* wp = ((it + 1) & 1) ? wt1 : wt0;
        __hip_atomic_store(&wp[s * 128 + t], pk, __ATOMIC_RELAXED,
                           __HIP_MEMORY_SCOPE_AGENT);
      }
    }
  }

  if (t < 128) Sbuf[(size_t)b * 512 + s * 128 + t] = Sreg;
}

// ---------------------------------------------------------------------------
// K7: epilogue  x = Minv * (alpha * A^T S - q)
// ---------------------------------------------------------------------------
__global__ __launch_bounds__(256) void k_final(
    const float* __restrict__ A, const float* __restrict__ q,
    const float* __restrict__ Mi, const float* __restrict__ Sbuf,
    float* __restrict__ xout) {
  int b = blockIdx.x, t = threadIdx.x;
  __shared__ float Ssh[512];
  __shared__ float uu[256];
  for (int i = t; i < 512; i += 256) Ssh[i] = Sbuf[(size_t)b * 512 + i];
  __syncthreads();
  const float* Ab = A + (size_t)b * 131072;
  float acc = 0.0f;
  for (int m = 0; m < 512; ++m) acc += Ab[(size_t)m * 256 + t] * Ssh[m];
  uu[t] = ALPHA_C * acc - q[(size_t)b * 256 + t];
  __syncthreads();
  const float* Mb = Mi + (size_t)b * 65536;
  float x = 0.0f;
  for (int kk = 0; kk < 256; ++kk) x += Mb[(size_t)kk * 256 + t] * uu[kk];
  xout[(size_t)b * 256 + t] = x;
}

// ---------------------------------------------------------------------------
extern "C" void kernel_launch(void* const* d_in, const int* in_sizes, int n_in,
                              void* d_out, int out_size, void* d_ws, size_t ws_size,
                              hipStream_t stream) {
  (void)in_sizes; (void)n_in; (void)out_size; (void)ws_size;
  const float* P = (const float*)d_in[0];
  const float* q = (const float*)d_in[1];
  const float* Av = (const float*)d_in[2];
  const float* lv = (const float*)d_in[3];
  const float* uv = (const float*)d_in[4];
  float* xout = (float*)d_out;

  float* ws = (float*)d_ws;
  float* At = ws;                       // 64*256*512; dies after k_matvec_d
  float* F  = ws;                       // alias of At; dies after ntgemm G
  float* Mi = ws + 8388608;             // 64*256*256
  float* Mk = ws + 12582912;            // dies after k_invert
  float* Gp = ws + 12582912;            // packed fp16 G: 64*131072 u32 = 32MB
  float* hv = ws + 29360128;            // 64*256
  float* dv = ws + 29376512;            // 64*512
  float* Sbuf = ws + 29409280;          // 64*512
  unsigned long long* wtag = (unsigned long long*)ws;  // overlays dead At/F

  k_transpose<<<dim3(8, 16, 64), dim3(32, 8), 0, stream>>>(Av, At);
  k_ntgemm<<<dim3(4, 64), 256, 0, stream>>>(At, At, Mk, 256, 256, 512,
                                            131072LL, 131072LL, 65536LL,
                                            RHO_C, P, 2, 0);
  k_invert<<<64, 512, 0, stream>>>(Mk, Mi);
  k_matvec_h<<<64, 256, 0, stream>>>(Mi, q, hv);
  k_matvec_d<<<64, 512, 0, stream>>>(At, hv, dv);
  k_ntgemm<<<dim3(8, 64), 256, 0, stream>>>(Av, Mi, F, 512, 256, 256,
                                            131072LL, 65536LL, 131072LL,
                                            1.0f, nullptr, 2, 0);
  // G-GEMM writes packed fp16 directly (bsC in u32 units: 4*32768 per batch)
  k_ntgemm<<<dim3(16, 64), 256, 0, stream>>>(F, Av, Gp, 512, 512, 256,
                                             131072LL, 131072LL, 131072LL,
                                             1.0f, nullptr, 4, 1);
  k_admm4<<<256, 512, 0, stream>>>((const unsigned*)Gp, dv, lv, uv, wtag, Sbuf);
  k_final<<<64, 256, 0, stream>>>(Av, q, Mi, Sbuf, xout);
}